// Round 5
// baseline (2390.047 us; speedup 1.0000x reference)
//
#include <hip/hip_runtime.h>
#include <hip/hip_bf16.h>

#define NB   16      // batch
#define FDIM 2048    // lstm hidden
#define GDIM 8192    // 4*FDIM gates
#define WSEQ 32      // seq len
#define CDIM 256
#define CBD  64
#define HGT  32

typedef float f32x4 __attribute__((ext_vector_type(4)));
typedef long  l64x2 __attribute__((ext_vector_type(2)));
typedef unsigned char u8;

__device__ __forceinline__ float sigf(float x) { return 1.f / (1.f + __expf(-x)); }

__device__ __forceinline__ u8 f32_to_fp8(float f) {
    int w = __builtin_amdgcn_cvt_pk_fp8_f32(f, f, 0, 0);
    return (u8)(w & 0xff);
}

// ---------------------------------------------------------------------------
// Coalesced weight pack -> fp8 e4m3.
// Block = (mat, tile). Tile tIdx = jt*2 + p; column c(0..15): gate = 2p+(c>>3),
// j = jt*8+(c&7), source row r = gate*2048 + j. Output:
// W[tile][kc2(0..63)][lane(0..63)][16B]; bytes0-7 = frag kc=2kc2,
// bytes8-15 = kc=2kc2+1; byte i of frag (kc,lane): k = kc*32+(lane>>4)*8+i,
// col = lane&15. k<2048 -> w_ih[k], else w_hh[k-2048].
// Reads: full rows coalesced; transpose via padded LDS byte tile.
// ---------------------------------------------------------------------------
__global__ __launch_bounds__(256) void pack_w(
        const float* __restrict__ wih0, const float* __restrict__ whh0,
        const float* __restrict__ wih1, const float* __restrict__ whh1,
        u8* __restrict__ W0, u8* __restrict__ W1) {
    __shared__ u8 FW[16][4112];   // [c][k], +16 pad
    int b = blockIdx.x;           // 0..1023
    int mat = b >> 9, tile = b & 511;
    const float* wih = mat ? wih1 : wih0;
    const float* whh = mat ? whh1 : whh0;
    int p = tile & 1, jt = tile >> 1;
    int tid = threadIdx.x;
    for (int it = 0; it < 32; ++it) {     // 2 src halves x 16 rows
        int c = it & 15, srcsel = it >> 4;
        int gate = p * 2 + (c >> 3);
        int r = gate * FDIM + jt * 8 + (c & 7);
        const float* s = (srcsel ? whh : wih) + (size_t)r * FDIM + tid * 8;
        float4 f0 = *(const float4*)(s);
        float4 f1 = *(const float4*)(s + 4);
        int w0 = __builtin_amdgcn_cvt_pk_fp8_f32(f0.x, f0.y, 0, 0);
        w0     = __builtin_amdgcn_cvt_pk_fp8_f32(f0.z, f0.w, w0, 1);
        int w1 = __builtin_amdgcn_cvt_pk_fp8_f32(f1.x, f1.y, 0, 0);
        w1     = __builtin_amdgcn_cvt_pk_fp8_f32(f1.z, f1.w, w1, 1);
        *(int2*)&FW[c][srcsel * 2048 + tid * 8] = make_int2(w0, w1);
    }
    __syncthreads();
    u8* base = (mat ? W1 : W0) + (size_t)tile * 65536;
#pragma unroll
    for (int w = 0; w < 16; ++w) {
        int q = w * 256 + tid;            // kc2*64 + lane
        int kc2 = q >> 6, lane = q & 63;
        int c = lane & 15, kg = lane >> 4;
        l64x2 v;
        v.x = *(const long*)&FW[c][kc2 * 64 + kg * 8];
        v.y = *(const long*)&FW[c][kc2 * 64 + 32 + kg * 8];
        *(l64x2*)(base + (size_t)q * 16) = v;
    }
}

__global__ void bias_k(const float* __restrict__ bih0, const float* __restrict__ bhh0,
                       const float* __restrict__ bih1, const float* __restrict__ bhh1,
                       float* __restrict__ b0, float* __restrict__ b1) {
    int i = blockIdx.x * blockDim.x + threadIdx.x;
    if (i < GDIM)            b0[i] = bih0[i] + bhh0[i];
    else if (i < 2 * GDIM) { int j = i - GDIM; b1[j] = bih1[j] + bhh1[j]; }
}

// ---------------------------------------------------------------------------
// 1x1 conv-in; emit seq in PACKED A-fragment layout:
//   seqbP[t] : [64 kc][64 lane][8B], lane = kg*16 + n, byte i -> k = kc*32+kg*8+i
// ---------------------------------------------------------------------------
__global__ __launch_bounds__(256) void conv_in(const float* __restrict__ latent,
                        const float* __restrict__ w_in, const float* __restrict__ b_in,
                        u8* __restrict__ seqbP) {
    __shared__ float lat[CDIM * HGT]; // [c][h] 32 KiB
    __shared__ float hv[FDIM];        // 8 KiB
    int b = blockIdx.x; int n = b >> 5; int t = b & 31;
    int tid = threadIdx.x;
    for (int i = 0; i < 32; ++i) {
        int flat = i * 256 + tid;         // c*32+h
        int c = flat >> 5, h = flat & 31;
        lat[flat] = latent[(((size_t)n * CDIM + c) * WSEQ + t) * HGT + h];
    }
    __syncthreads();
    int cb = tid & 63;
    int hb = tid >> 6;
    float acc[8];
#pragma unroll
    for (int k = 0; k < 8; ++k) acc[k] = b_in[cb];
    for (int c = 0; c < CDIM; ++c) {
        float wv = w_in[cb * CDIM + c];
#pragma unroll
        for (int k = 0; k < 8; ++k) acc[k] += lat[c * HGT + (hb + k * 4)] * wv;
    }
#pragma unroll
    for (int k = 0; k < 8; ++k) hv[k * 256 + tid] = acc[k];   // hv[f], f = h*64+cb
    __syncthreads();
    union { u8 by[8]; long l; } pk;
#pragma unroll
    for (int i = 0; i < 8; ++i) pk.by[i] = f32_to_fp8(hv[tid * 8 + i]);
    *(long*)(seqbP + (size_t)t * 32768 + (tid >> 2) * 512 + (tid & 3) * 128 + n * 8) = pk.l;
}

// ---------------------------------------------------------------------------
// X0pre[t*16+m][rr] = seq[t] @ w_ih0^T, packed col order rr = ntile*16 + c.
// grid 512 = one block per ntile; 8 waves x 4 t-tiles; A packed & coalesced.
// ---------------------------------------------------------------------------
__global__ __launch_bounds__(512) void x0_gemm(const u8* __restrict__ seqbP,
                                               const u8* __restrict__ W0,
                                               float* __restrict__ x0) {
    int ntile = blockIdx.x;            // 0..511
    int wave = threadIdx.x >> 6, l = threadIdx.x & 63;
    int la = l & 15, kg = l >> 4;
    f32x4 acc[4];
#pragma unroll
    for (int i = 0; i < 4; ++i) acc[i] = (f32x4){0.f, 0.f, 0.f, 0.f};
    const u8* Bb = W0 + (size_t)ntile * 64 * 64 * 16;
#pragma unroll 2
    for (int kc2 = 0; kc2 < 32; ++kc2) {
        l64x2 bp = *(const l64x2*)(Bb + ((size_t)kc2 * 64 + l) * 16);
#pragma unroll
        for (int i = 0; i < 4; ++i) {
            int t = wave * 4 + i;
            const u8* Ab = seqbP + (size_t)t * 32768 + (size_t)(2 * kc2) * 512 + l * 8;
            long a0 = *(const long*)Ab;
            long a1 = *(const long*)(Ab + 512);
            acc[i] = __builtin_amdgcn_mfma_f32_16x16x32_fp8_fp8(a0, bp.x, acc[i], 0, 0, 0);
            acc[i] = __builtin_amdgcn_mfma_f32_16x16x32_fp8_fp8(a1, bp.y, acc[i], 0, 0, 0);
        }
    }
#pragma unroll
    for (int i = 0; i < 4; ++i) {
        int t = wave * 4 + i;
#pragma unroll
        for (int q = 0; q < 4; ++q)
            x0[((size_t)(t * 16 + kg * 4 + q)) * GDIM + ntile * 16 + la] = acc[i][q];
    }
}

// ---------------------------------------------------------------------------
// LSTM phase body (device). A: packed activations [128 kc][64 lane][8B].
// 16 waves: wave = p(gate pair)*8 + ke(k-eighth). B from global (streamed)
// or from the block's LDS W1 slice. Tail: LSTM cell, h written fp8 into the
// h-half of hA and x-half of hB (contiguous 128 B per block).
// ---------------------------------------------------------------------------
template<int KCC, bool LDSB>
__device__ __forceinline__ void phase_body(
        int jt, int tid,
        const u8* __restrict__ A, const u8* __restrict__ Bp, const uint4* blds,
        const float* __restrict__ xpre, const float* __restrict__ bias,
        float* __restrict__ cbuf, u8* __restrict__ hA, u8* __restrict__ hB,
        float* __restrict__ seqSlot, int kcStart, float* part) {
    int wave = tid >> 6, l = tid & 63;
    int p = wave >> 3, ke = wave & 7;
    int la = l & 15, kg = l >> 4;
    constexpr int SL  = KCC / 8;   // kc chunks per wave
    constexpr int SL2 = SL / 2;
    int kc0 = kcStart + ke * SL;
    union U16 { uint4 u; l64x2 l; };
    U16 bfr[SL2];
    long afr[SL];
    const u8* Ab = A + (size_t)kc0 * 512 + l * 8;
#pragma unroll
    for (int i = 0; i < SL; ++i) afr[i] = *(const long*)(Ab + (size_t)i * 512);
    if (LDSB) {
        int base = (p * 64 + (kc0 >> 1)) * 64 + l;
#pragma unroll
        for (int i = 0; i < SL2; ++i) bfr[i].u = blds[base + i * 64];
    } else {
        const u8* Bb = Bp + ((size_t)((jt * 2 + p) * 64 + (kc0 >> 1)) * 64 + l) * 16;
#pragma unroll
        for (int i = 0; i < SL2; ++i) bfr[i].u = *(const uint4*)(Bb + (size_t)i * 1024);
    }
    f32x4 acc0 = (f32x4){0.f, 0.f, 0.f, 0.f};
    f32x4 acc1 = (f32x4){0.f, 0.f, 0.f, 0.f};
#pragma unroll
    for (int i = 0; i < SL2; ++i) {
        acc0 = __builtin_amdgcn_mfma_f32_16x16x32_fp8_fp8(afr[2 * i],     bfr[i].l.x, acc0, 0, 0, 0);
        acc1 = __builtin_amdgcn_mfma_f32_16x16x32_fp8_fp8(afr[2 * i + 1], bfr[i].l.y, acc1, 0, 0, 0);
    }
    f32x4 acc = acc0 + acc1;
    __syncthreads();   // protect part[] from the previous body's tail readers
#pragma unroll
    for (int q = 0; q < 4; ++q) part[(wave * 16 + kg * 4 + q) * 17 + la] = acc[q];
    __syncthreads();
    if (tid < 128) {
        int m = tid >> 3, jj = tid & 7;
        float gi = 0.f, gf = 0.f, gg = 0.f, go = 0.f;
#pragma unroll
        for (int e = 0; e < 8; ++e) {
            gi += part[(e * 16 + m) * 17 + jj];
            gf += part[(e * 16 + m) * 17 + 8 + jj];
            gg += part[((8 + e) * 16 + m) * 17 + jj];
            go += part[((8 + e) * 16 + m) * 17 + 8 + jj];
        }
        int j = jt * 8 + jj;
        gi += bias[0 * FDIM + j];
        gf += bias[1 * FDIM + j];
        gg += bias[2 * FDIM + j];
        go += bias[3 * FDIM + j];
        if (xpre) {
            const float* xb = xpre + (size_t)m * GDIM + jt * 32;  // packed order
            gi += xb[jj]; gf += xb[8 + jj]; gg += xb[16 + jj]; go += xb[24 + jj];
        }
        float c  = cbuf[m * FDIM + j];
        float cn = sigf(gf) * c + sigf(gi) * tanhf(gg);
        float h  = sigf(go) * tanhf(cn);
        cbuf[m * FDIM + j] = cn;
        u8 hb = f32_to_fp8(h);
        int pos = (jt >> 2) * 512 + (jt & 3) * 128 + tid;
        hA[32768 + pos] = hb;   // h-half
        hB[pos] = hb;           // x-half
        if (seqSlot) seqSlot[m * FDIM + j] = h;
    }
}

// Device-scope grid barrier: per-stage slot, release/acquire (XCD-safe).
__device__ __forceinline__ void grid_bar(unsigned* slot) {
    __syncthreads();
    if (threadIdx.x == 0) {
        __threadfence();
        __hip_atomic_fetch_add(slot, 1u, __ATOMIC_ACQ_REL, __HIP_MEMORY_SCOPE_AGENT);
        int guard = 0;
        while (__hip_atomic_load(slot, __ATOMIC_ACQUIRE, __HIP_MEMORY_SCOPE_AGENT) < 256u
               && ++guard < (1 << 22))
            __builtin_amdgcn_s_sleep(1);
        __threadfence();
    }
    __syncthreads();
}

// ---------------------------------------------------------------------------
// Persistent recurrence: all 126 LSTM phases, grid-sync'd. 256 blocks x 1024.
// Block jt owns features jt*8..jt*8+7 (all 4 gates). W1 slice lives in LDS.
// ---------------------------------------------------------------------------
__global__ __launch_bounds__(1024, 4) void recurrence(
        const u8* __restrict__ W0, const u8* __restrict__ W1,
        const float* __restrict__ X0,
        const float* __restrict__ b0, const float* __restrict__ b1,
        float* __restrict__ c0, float* __restrict__ c1,
        u8* __restrict__ a00, u8* __restrict__ a01,
        u8* __restrict__ a10, u8* __restrict__ a11,
        float* __restrict__ sqo, unsigned* __restrict__ bar) {
    __shared__ uint4 w1lds[8192];        // 128 KiB: this block's W1 slice
    __shared__ float part[16 * 16 * 17]; // 17 KiB
    int jt = blockIdx.x, tid = threadIdx.x;
    {
        const uint4* src = (const uint4*)(W1 + (size_t)jt * 131072);
        for (int i = tid; i < 8192; i += 1024) w1lds[i] = src[i];
    }
    __syncthreads();
    u8* a0arr[2] = {a00, a01};
    u8* a1arr[2] = {a10, a11};
    int stage = 0;
    // stage 0: L0[0] (h-half only; reads zeros, + X0[0])
    phase_body<64, false>(jt, tid, a00, W0, nullptr, X0, b0, c0,
                          a01, a10, nullptr, 64, part);
    grid_bar(bar + stage++);
    // fwd pair stages: L0[s+1] (stream W0) + L1[s] (LDS W1)
    for (int s = 0; s <= 30; ++s) {
        int p = s & 1;
        phase_body<64, false>(jt, tid, a0arr[1 - p], W0, nullptr,
                              X0 + (size_t)(s + 1) * NB * GDIM, b0, c0,
                              a0arr[p], a1arr[1 - p], nullptr, 64, part);
        phase_body<128, true>(jt, tid, a1arr[p], nullptr, w1lds, nullptr, b1, c1,
                              a1arr[1 - p], a0arr[1 - p], nullptr, 0, part);
        grid_bar(bar + stage++);
    }
    // s=31, L1 records first output
    phase_body<128, true>(jt, tid, a1arr[1], nullptr, w1lds, nullptr, b1, c1,
                          a1arr[0], a0arr[0], sqo, 0, part);
    grid_bar(bar + stage++);
    // AR region
    for (int s = 32; s < 63; ++s) {
        int p = s & 1;
        phase_body<128, false>(jt, tid, a0arr[p], W0, nullptr, nullptr, b0, c0,
                               a0arr[1 - p], a1arr[p], nullptr, 0, part);
        grid_bar(bar + stage++);
        phase_body<128, true>(jt, tid, a1arr[p], nullptr, w1lds, nullptr, b1, c1,
                              a1arr[1 - p], a0arr[1 - p],
                              sqo + (size_t)(s - 31) * NB * FDIM, 0, part);
        if (s != 62) grid_bar(bar + stage++);
    }
}

// copy latent -> out[:, :, 0:32, :]
__global__ void copy_lat(const float* __restrict__ latent, float* __restrict__ out) {
    size_t i = (size_t)blockIdx.x * blockDim.x + threadIdx.x;
    if (i >= (size_t)1048576) return;
    size_t blk = i >> 8;
    size_t within = i & 255;
    float4 v = ((const float4*)latent)[i];
    ((float4*)out)[blk * 512 + within] = v;
}

// gen half: out[n][c][32+t][h] = sum_cb seq_out[t][n][h*64+cb]*w_out[c][cb] + b_out[c]
__global__ __launch_bounds__(256) void gen_out(const float* __restrict__ seq_out,
                        const float* __restrict__ w_out, const float* __restrict__ b_out,
                        float* __restrict__ out) {
    __shared__ float row[32 * 65];
    int b = blockIdx.x; int n = b >> 5, t = b & 31;
    const float* src = seq_out + ((size_t)t * NB + n) * FDIM;
    for (int i = threadIdx.x; i < FDIM; i += 256)
        row[(i >> 6) * 65 + (i & 63)] = src[i];
    __syncthreads();
    for (int it = 0; it < 32; ++it) {
        int o = it * 256 + threadIdx.x;
        int c = o >> 5, h = o & 31;
        float acc = b_out[c];
#pragma unroll
        for (int cb = 0; cb < CBD; ++cb) acc += row[h * 65 + cb] * w_out[c * CBD + cb];
        out[(((size_t)n * CDIM + c) * 64 + 32 + t) * HGT + h] = acc;
    }
}

extern "C" void kernel_launch(void* const* d_in, const int* in_sizes, int n_in,
                              void* d_out, int out_size, void* d_ws, size_t ws_size,
                              hipStream_t stream) {
    const float* latent = (const float*)d_in[0];
    const float* w_in   = (const float*)d_in[1];
    const float* b_in   = (const float*)d_in[2];
    const float* w_ih0  = (const float*)d_in[3];
    const float* w_hh0  = (const float*)d_in[4];
    const float* b_ih0  = (const float*)d_in[5];
    const float* b_hh0  = (const float*)d_in[6];
    const float* w_ih1  = (const float*)d_in[7];
    const float* w_hh1  = (const float*)d_in[8];
    const float* b_ih1  = (const float*)d_in[9];
    const float* b_hh1  = (const float*)d_in[10];
    const float* w_out  = (const float*)d_in[11];
    const float* b_out  = (const float*)d_in[12];
    float* out = (float*)d_out;
    char* ws = (char*)d_ws;

    size_t off = 0;
    u8*    W0   = (u8*)(ws + off); off += (size_t)512 * 65536;             // 32 MiB
    u8*    W1   = (u8*)(ws + off); off += (size_t)512 * 65536;             // 32 MiB
    float* X0   = (float*)(ws + off); off += (size_t)WSEQ * NB * GDIM * 4; // 16 MiB
    u8*    seqbP= (u8*)(ws + off); off += (size_t)WSEQ * 32768;            // 1 MiB
    float* sqo  = (float*)(ws + off); off += (size_t)WSEQ * NB * FDIM * 4; // 4 MiB
    char*  zbase = ws + off;
    u8* a00 = (u8*)(ws + off); off += 65536;
    u8* a01 = (u8*)(ws + off); off += 65536;
    u8* a10 = (u8*)(ws + off); off += 65536;
    u8* a11 = (u8*)(ws + off); off += 65536;
    float* c0 = (float*)(ws + off); off += (size_t)NB * FDIM * 4;
    float* c1 = (float*)(ws + off); off += (size_t)NB * FDIM * 4;
    unsigned* bar = (unsigned*)(ws + off); off += 512;                     // 128 slots
    size_t zbytes = (size_t)(ws + off - zbase);
    float* b0 = (float*)(ws + off); off += (size_t)GDIM * 4;
    float* b1 = (float*)(ws + off); off += (size_t)GDIM * 4;

    if (ws_size < off) {
        hipMemsetAsync(d_out, 0, (size_t)out_size * 4, stream);
        return;
    }

    hipMemsetAsync(zbase, 0, zbytes, stream);
    pack_w<<<1024, 256, 0, stream>>>(w_ih0, w_hh0, w_ih1, w_hh1, W0, W1);
    bias_k<<<64, 256, 0, stream>>>(b_ih0, b_hh0, b_ih1, b_hh1, b0, b1);
    conv_in<<<512, 256, 0, stream>>>(latent, w_in, b_in, seqbP);
    x0_gemm<<<512, 512, 0, stream>>>(seqbP, W0, X0);
    recurrence<<<256, 1024, 0, stream>>>(W0, W1, X0, b0, b1, c0, c1,
                                         a00, a01, a10, a11, sqo, bar);
    copy_lat<<<4096, 256, 0, stream>>>(latent, out);
    gen_out<<<512, 256, 0, stream>>>(sqo, w_out, b_out, out);
}

// Round 6
// 1060.787 us; speedup vs baseline: 2.2531x; 2.2531x over previous
//
#include <hip/hip_runtime.h>
#include <hip/hip_bf16.h>

#define NB   16      // batch
#define FDIM 2048    // lstm hidden
#define GDIM 8192    // 4*FDIM gates
#define WSEQ 32      // seq len
#define CDIM 256
#define CBD  64
#define HGT  32

typedef float f32x4 __attribute__((ext_vector_type(4)));
typedef long  l64x2 __attribute__((ext_vector_type(2)));
typedef unsigned char u8;

#define PSTR 18      // part[] stride: 2-way bank aliasing (free), was 17 (4-way)
#define BARSTRIDE 288  // u32 per stage: 8 group lines + 1 root line, 128B apart

__device__ __forceinline__ float sigf(float x) { return 1.f / (1.f + __expf(-x)); }

__device__ __forceinline__ u8 f32_to_fp8(float f) {
    int w = __builtin_amdgcn_cvt_pk_fp8_f32(f, f, 0, 0);
    return (u8)(w & 0xff);
}

// ---------------------------------------------------------------------------
// Coalesced weight pack -> fp8 e4m3 (layout as R5).
// ---------------------------------------------------------------------------
__global__ __launch_bounds__(256) void pack_w(
        const float* __restrict__ wih0, const float* __restrict__ whh0,
        const float* __restrict__ wih1, const float* __restrict__ whh1,
        u8* __restrict__ W0, u8* __restrict__ W1) {
    __shared__ u8 FW[16][4112];   // [c][k], +16 pad
    int b = blockIdx.x;           // 0..1023
    int mat = b >> 9, tile = b & 511;
    const float* wih = mat ? wih1 : wih0;
    const float* whh = mat ? whh1 : whh0;
    int p = tile & 1, jt = tile >> 1;
    int tid = threadIdx.x;
    for (int it = 0; it < 32; ++it) {     // 2 src halves x 16 rows
        int c = it & 15, srcsel = it >> 4;
        int gate = p * 2 + (c >> 3);
        int r = gate * FDIM + jt * 8 + (c & 7);
        const float* s = (srcsel ? whh : wih) + (size_t)r * FDIM + tid * 8;
        float4 f0 = *(const float4*)(s);
        float4 f1 = *(const float4*)(s + 4);
        int w0 = __builtin_amdgcn_cvt_pk_fp8_f32(f0.x, f0.y, 0, 0);
        w0     = __builtin_amdgcn_cvt_pk_fp8_f32(f0.z, f0.w, w0, 1);
        int w1 = __builtin_amdgcn_cvt_pk_fp8_f32(f1.x, f1.y, 0, 0);
        w1     = __builtin_amdgcn_cvt_pk_fp8_f32(f1.z, f1.w, w1, 1);
        *(int2*)&FW[c][srcsel * 2048 + tid * 8] = make_int2(w0, w1);
    }
    __syncthreads();
    u8* base = (mat ? W1 : W0) + (size_t)tile * 65536;
#pragma unroll
    for (int w = 0; w < 16; ++w) {
        int q = w * 256 + tid;            // kc2*64 + lane
        int kc2 = q >> 6, lane = q & 63;
        int c = lane & 15, kg = lane >> 4;
        l64x2 v;
        v.x = *(const long*)&FW[c][kc2 * 64 + kg * 8];
        v.y = *(const long*)&FW[c][kc2 * 64 + 32 + kg * 8];
        *(l64x2*)(base + (size_t)q * 16) = v;
    }
}

__global__ void bias_k(const float* __restrict__ bih0, const float* __restrict__ bhh0,
                       const float* __restrict__ bih1, const float* __restrict__ bhh1,
                       float* __restrict__ b0, float* __restrict__ b1) {
    int i = blockIdx.x * blockDim.x + threadIdx.x;
    if (i < GDIM)            b0[i] = bih0[i] + bhh0[i];
    else if (i < 2 * GDIM) { int j = i - GDIM; b1[j] = bih1[j] + bhh1[j]; }
}

// ---------------------------------------------------------------------------
// 1x1 conv-in; emit seq in PACKED A-fragment layout:
//   seqbP[t] : [64 kc][64 lane][8B], lane = kg*16 + n, byte i -> k = kc*32+kg*8+i
// ---------------------------------------------------------------------------
__global__ __launch_bounds__(256) void conv_in(const float* __restrict__ latent,
                        const float* __restrict__ w_in, const float* __restrict__ b_in,
                        u8* __restrict__ seqbP) {
    __shared__ float lat[CDIM * HGT]; // [c][h] 32 KiB
    __shared__ float hv[FDIM];        // 8 KiB
    int b = blockIdx.x; int n = b >> 5; int t = b & 31;
    int tid = threadIdx.x;
    for (int i = 0; i < 32; ++i) {
        int flat = i * 256 + tid;         // c*32+h
        int c = flat >> 5, h = flat & 31;
        lat[flat] = latent[(((size_t)n * CDIM + c) * WSEQ + t) * HGT + h];
    }
    __syncthreads();
    int cb = tid & 63;
    int hb = tid >> 6;
    float acc[8];
#pragma unroll
    for (int k = 0; k < 8; ++k) acc[k] = b_in[cb];
    for (int c = 0; c < CDIM; ++c) {
        float wv = w_in[cb * CDIM + c];
#pragma unroll
        for (int k = 0; k < 8; ++k) acc[k] += lat[c * HGT + (hb + k * 4)] * wv;
    }
#pragma unroll
    for (int k = 0; k < 8; ++k) hv[k * 256 + tid] = acc[k];   // hv[f], f = h*64+cb
    __syncthreads();
    union { u8 by[8]; long l; } pk;
#pragma unroll
    for (int i = 0; i < 8; ++i) pk.by[i] = f32_to_fp8(hv[tid * 8 + i]);
    *(long*)(seqbP + (size_t)t * 32768 + (tid >> 2) * 512 + (tid & 3) * 128 + n * 8) = pk.l;
}

// ---------------------------------------------------------------------------
// X0pre[t*16+m][rr] = seq[t] @ w_ih0^T, packed col order rr = ntile*16 + c.
// ---------------------------------------------------------------------------
__global__ __launch_bounds__(512) void x0_gemm(const u8* __restrict__ seqbP,
                                               const u8* __restrict__ W0,
                                               float* __restrict__ x0) {
    int ntile = blockIdx.x;            // 0..511
    int wave = threadIdx.x >> 6, l = threadIdx.x & 63;
    int la = l & 15, kg = l >> 4;
    f32x4 acc[4];
#pragma unroll
    for (int i = 0; i < 4; ++i) acc[i] = (f32x4){0.f, 0.f, 0.f, 0.f};
    const u8* Bb = W0 + (size_t)ntile * 64 * 64 * 16;
#pragma unroll 2
    for (int kc2 = 0; kc2 < 32; ++kc2) {
        l64x2 bp = *(const l64x2*)(Bb + ((size_t)kc2 * 64 + l) * 16);
#pragma unroll
        for (int i = 0; i < 4; ++i) {
            int t = wave * 4 + i;
            const u8* Ab = seqbP + (size_t)t * 32768 + (size_t)(2 * kc2) * 512 + l * 8;
            long a0 = *(const long*)Ab;
            long a1 = *(const long*)(Ab + 512);
            acc[i] = __builtin_amdgcn_mfma_f32_16x16x32_fp8_fp8(a0, bp.x, acc[i], 0, 0, 0);
            acc[i] = __builtin_amdgcn_mfma_f32_16x16x32_fp8_fp8(a1, bp.y, acc[i], 0, 0, 0);
        }
    }
#pragma unroll
    for (int i = 0; i < 4; ++i) {
        int t = wave * 4 + i;
#pragma unroll
        for (int q = 0; q < 4; ++q)
            x0[((size_t)(t * 16 + kg * 4 + q)) * GDIM + ntile * 16 + la] = acc[i][q];
    }
}

// ---------------------------------------------------------------------------
// LSTM phase body. Cross-block activations move via sc1 (agent-scope relaxed
// atomics): h byte-stores go straight to L3; A fragment loads bypass L2.
// So no cache invalidations are ever needed, and W0 stays hot in per-XCD L2.
// ---------------------------------------------------------------------------
template<int KCC, bool LDSB>
__device__ __forceinline__ void phase_body(
        int jt, int tid,
        const u8* __restrict__ A, const u8* __restrict__ Bp, const uint4* blds,
        const float* __restrict__ xpre, const float* __restrict__ bias,
        float* __restrict__ cbuf, u8* __restrict__ hA, u8* __restrict__ hB,
        float* __restrict__ seqSlot, int kcStart, float* part) {
    int wave = tid >> 6, l = tid & 63;
    int p = wave >> 3, ke = wave & 7;
    int la = l & 15, kg = l >> 4;
    constexpr int SL  = KCC / 8;   // kc chunks per wave
    constexpr int SL2 = SL / 2;
    int kc0 = kcStart + ke * SL;
    union U16 { uint4 u; l64x2 l; };
    U16 bfr[SL2];
    long afr[SL];
    const u8* Ab = A + (size_t)kc0 * 512 + l * 8;
#pragma unroll
    for (int i = 0; i < SL; ++i)
        afr[i] = __hip_atomic_load((const long*)(Ab + (size_t)i * 512),
                                   __ATOMIC_RELAXED, __HIP_MEMORY_SCOPE_AGENT);
    if (LDSB) {
        int base = (p * 64 + (kc0 >> 1)) * 64 + l;
#pragma unroll
        for (int i = 0; i < SL2; ++i) bfr[i].u = blds[base + i * 64];
    } else {
        const u8* Bb = Bp + ((size_t)((jt * 2 + p) * 64 + (kc0 >> 1)) * 64 + l) * 16;
#pragma unroll
        for (int i = 0; i < SL2; ++i) bfr[i].u = *(const uint4*)(Bb + (size_t)i * 1024);
    }
    f32x4 acc0 = (f32x4){0.f, 0.f, 0.f, 0.f};
    f32x4 acc1 = (f32x4){0.f, 0.f, 0.f, 0.f};
#pragma unroll
    for (int i = 0; i < SL2; ++i) {
        acc0 = __builtin_amdgcn_mfma_f32_16x16x32_fp8_fp8(afr[2 * i],     bfr[i].l.x, acc0, 0, 0, 0);
        acc1 = __builtin_amdgcn_mfma_f32_16x16x32_fp8_fp8(afr[2 * i + 1], bfr[i].l.y, acc1, 0, 0, 0);
    }
    f32x4 acc = acc0 + acc1;
    __syncthreads();   // protect part[] from the previous body's tail readers
#pragma unroll
    for (int q = 0; q < 4; ++q) part[(wave * 16 + kg * 4 + q) * PSTR + la] = acc[q];
    __syncthreads();
    if (tid < 128) {
        int m = tid >> 3, jj = tid & 7;
        float gi = 0.f, gf = 0.f, gg = 0.f, go = 0.f;
#pragma unroll
        for (int e = 0; e < 8; ++e) {
            gi += part[(e * 16 + m) * PSTR + jj];
            gf += part[(e * 16 + m) * PSTR + 8 + jj];
            gg += part[((8 + e) * 16 + m) * PSTR + jj];
            go += part[((8 + e) * 16 + m) * PSTR + 8 + jj];
        }
        int j = jt * 8 + jj;
        gi += bias[0 * FDIM + j];
        gf += bias[1 * FDIM + j];
        gg += bias[2 * FDIM + j];
        go += bias[3 * FDIM + j];
        if (xpre) {
            const float* xb = xpre + (size_t)m * GDIM + jt * 32;  // packed order
            gi += xb[jj]; gf += xb[8 + jj]; gg += xb[16 + jj]; go += xb[24 + jj];
        }
        float c  = cbuf[m * FDIM + j];
        float cn = sigf(gf) * c + sigf(gi) * tanhf(gg);
        float h  = sigf(go) * tanhf(cn);
        cbuf[m * FDIM + j] = cn;
        u8 hb = f32_to_fp8(h);
        int pos = (jt >> 2) * 512 + (jt & 3) * 128 + tid;
        __hip_atomic_store(hA + 32768 + pos, hb, __ATOMIC_RELAXED, __HIP_MEMORY_SCOPE_AGENT);
        __hip_atomic_store(hB + pos,         hb, __ATOMIC_RELAXED, __HIP_MEMORY_SCOPE_AGENT);
        if (seqSlot) seqSlot[m * FDIM + j] = h;
    }
}

// ---------------------------------------------------------------------------
// Hierarchical grid barrier: 8 group counters + 1 root, each on its own 128B
// line, one fresh set per stage. Arrivals: RELEASE RMW (waits prior vmem, no
// invalidate). Polls: RELAXED sc1 loads (no buffer_inv storm). Data coherence
// is carried entirely by the sc1 h-stores/A-loads, so no acquire is needed.
// ---------------------------------------------------------------------------
__device__ __forceinline__ void grid_bar(unsigned* base) {
    __syncthreads();
    if (threadIdx.x == 0) {
        unsigned* loc  = base + (blockIdx.x & 7) * 32;
        unsigned* root = base + 256;
        unsigned prev = __hip_atomic_fetch_add(loc, 1u, __ATOMIC_RELEASE,
                                               __HIP_MEMORY_SCOPE_AGENT);
        if (prev == 31u)
            __hip_atomic_fetch_add(root, 1u, __ATOMIC_RELEASE,
                                   __HIP_MEMORY_SCOPE_AGENT);
        int guard = 0;
        while (__hip_atomic_load(root, __ATOMIC_RELAXED, __HIP_MEMORY_SCOPE_AGENT) < 8u
               && ++guard < (1 << 24))
            __builtin_amdgcn_s_sleep(2);
    }
    __syncthreads();
}

// ---------------------------------------------------------------------------
// Persistent recurrence: all 126 LSTM phases, grid-sync'd. 256 blocks x 1024.
// Block jt owns features jt*8..jt*8+7 (all 4 gates). W1 slice lives in LDS;
// W0 slice (128 KiB/block) stays resident in per-XCD L2 (no invalidations).
// ---------------------------------------------------------------------------
__global__ __launch_bounds__(1024, 4) void recurrence(
        const u8* __restrict__ W0, const u8* __restrict__ W1,
        const float* __restrict__ X0,
        const float* __restrict__ b0, const float* __restrict__ b1,
        float* __restrict__ c0, float* __restrict__ c1,
        u8* __restrict__ a00, u8* __restrict__ a01,
        u8* __restrict__ a10, u8* __restrict__ a11,
        float* __restrict__ sqo, unsigned* __restrict__ bar) {
    __shared__ uint4 w1lds[8192];          // 128 KiB: this block's W1 slice
    __shared__ float part[16 * 16 * PSTR]; // 18 KiB
    int jt = blockIdx.x, tid = threadIdx.x;
    {
        const uint4* src = (const uint4*)(W1 + (size_t)jt * 131072);
        for (int i = tid; i < 8192; i += 1024) w1lds[i] = src[i];
    }
    __syncthreads();
    u8* a0arr[2] = {a00, a01};
    u8* a1arr[2] = {a10, a11};
    unsigned* bs = bar;
    // stage 0: L0[0] (h-half only; reads zeros, + X0[0])
    phase_body<64, false>(jt, tid, a00, W0, nullptr, X0, b0, c0,
                          a01, a10, nullptr, 64, part);
    grid_bar(bs); bs += BARSTRIDE;
    // fwd pair stages: L0[s+1] (stream W0 from L2) + L1[s] (LDS W1)
    for (int s = 0; s <= 30; ++s) {
        int p = s & 1;
        phase_body<64, false>(jt, tid, a0arr[1 - p], W0, nullptr,
                              X0 + (size_t)(s + 1) * NB * GDIM, b0, c0,
                              a0arr[p], a1arr[1 - p], nullptr, 64, part);
        phase_body<128, true>(jt, tid, a1arr[p], nullptr, w1lds, nullptr, b1, c1,
                              a1arr[1 - p], a0arr[1 - p], nullptr, 0, part);
        grid_bar(bs); bs += BARSTRIDE;
    }
    // s=31, L1 records first output
    phase_body<128, true>(jt, tid, a1arr[1], nullptr, w1lds, nullptr, b1, c1,
                          a1arr[0], a0arr[0], sqo, 0, part);
    grid_bar(bs); bs += BARSTRIDE;
    // AR region
    for (int s = 32; s < 63; ++s) {
        int p = s & 1;
        phase_body<128, false>(jt, tid, a0arr[p], W0, nullptr, nullptr, b0, c0,
                               a0arr[1 - p], a1arr[p], nullptr, 0, part);
        grid_bar(bs); bs += BARSTRIDE;
        phase_body<128, true>(jt, tid, a1arr[p], nullptr, w1lds, nullptr, b1, c1,
                              a1arr[1 - p], a0arr[1 - p],
                              sqo + (size_t)(s - 31) * NB * FDIM, 0, part);
        if (s != 62) { grid_bar(bs); bs += BARSTRIDE; }
    }
}

// copy latent -> out[:, :, 0:32, :]
__global__ void copy_lat(const float* __restrict__ latent, float* __restrict__ out) {
    size_t i = (size_t)blockIdx.x * blockDim.x + threadIdx.x;
    if (i >= (size_t)1048576) return;
    size_t blk = i >> 8;
    size_t within = i & 255;
    float4 v = ((const float4*)latent)[i];
    ((float4*)out)[blk * 512 + within] = v;
}

// gen half: out[n][c][32+t][h] = sum_cb seq_out[t][n][h*64+cb]*w_out[c][cb] + b_out[c]
__global__ __launch_bounds__(256) void gen_out(const float* __restrict__ seq_out,
                        const float* __restrict__ w_out, const float* __restrict__ b_out,
                        float* __restrict__ out) {
    __shared__ float row[32 * 65];
    int b = blockIdx.x; int n = b >> 5, t = b & 31;
    const float* src = seq_out + ((size_t)t * NB + n) * FDIM;
    for (int i = threadIdx.x; i < FDIM; i += 256)
        row[(i >> 6) * 65 + (i & 63)] = src[i];
    __syncthreads();
    for (int it = 0; it < 32; ++it) {
        int o = it * 256 + threadIdx.x;
        int c = o >> 5, h = o & 31;
        float acc = b_out[c];
#pragma unroll
        for (int cb = 0; cb < CBD; ++cb) acc += row[h * 65 + cb] * w_out[c * CBD + cb];
        out[(((size_t)n * CDIM + c) * 64 + 32 + t) * HGT + h] = acc;
    }
}

extern "C" void kernel_launch(void* const* d_in, const int* in_sizes, int n_in,
                              void* d_out, int out_size, void* d_ws, size_t ws_size,
                              hipStream_t stream) {
    const float* latent = (const float*)d_in[0];
    const float* w_in   = (const float*)d_in[1];
    const float* b_in   = (const float*)d_in[2];
    const float* w_ih0  = (const float*)d_in[3];
    const float* w_hh0  = (const float*)d_in[4];
    const float* b_ih0  = (const float*)d_in[5];
    const float* b_hh0  = (const float*)d_in[6];
    const float* w_ih1  = (const float*)d_in[7];
    const float* w_hh1  = (const float*)d_in[8];
    const float* b_ih1  = (const float*)d_in[9];
    const float* b_hh1  = (const float*)d_in[10];
    const float* w_out  = (const float*)d_in[11];
    const float* b_out  = (const float*)d_in[12];
    float* out = (float*)d_out;
    char* ws = (char*)d_ws;

    size_t off = 0;
    u8*    W0   = (u8*)(ws + off); off += (size_t)512 * 65536;             // 32 MiB
    u8*    W1   = (u8*)(ws + off); off += (size_t)512 * 65536;             // 32 MiB
    float* X0   = (float*)(ws + off); off += (size_t)WSEQ * NB * GDIM * 4; // 16 MiB
    u8*    seqbP= (u8*)(ws + off); off += (size_t)WSEQ * 32768;            // 1 MiB
    float* sqo  = (float*)(ws + off); off += (size_t)WSEQ * NB * FDIM * 4; // 4 MiB
    char*  zbase = ws + off;
    u8* a00 = (u8*)(ws + off); off += 65536;
    u8* a01 = (u8*)(ws + off); off += 65536;
    u8* a10 = (u8*)(ws + off); off += 65536;
    u8* a11 = (u8*)(ws + off); off += 65536;
    float* c0 = (float*)(ws + off); off += (size_t)NB * FDIM * 4;
    float* c1 = (float*)(ws + off); off += (size_t)NB * FDIM * 4;
    unsigned* bar = (unsigned*)(ws + off); off += (size_t)96 * BARSTRIDE * 4; // 108 KiB
    size_t zbytes = (size_t)(ws + off - zbase);
    float* b0 = (float*)(ws + off); off += (size_t)GDIM * 4;
    float* b1 = (float*)(ws + off); off += (size_t)GDIM * 4;

    if (ws_size < off) {
        hipMemsetAsync(d_out, 0, (size_t)out_size * 4, stream);
        return;
    }

    hipMemsetAsync(zbase, 0, zbytes, stream);
    pack_w<<<1024, 256, 0, stream>>>(w_ih0, w_hh0, w_ih1, w_hh1, W0, W1);
    bias_k<<<64, 256, 0, stream>>>(b_ih0, b_hh0, b_ih1, b_hh1, b0, b1);
    conv_in<<<512, 256, 0, stream>>>(latent, w_in, b_in, seqbP);
    x0_gemm<<<512, 512, 0, stream>>>(seqbP, W0, X0);
    recurrence<<<256, 1024, 0, stream>>>(W0, W1, X0, b0, b1, c0, c1,
                                         a00, a01, a10, a11, sqo, bar);
    copy_lat<<<4096, 256, 0, stream>>>(latent, out);
    gen_out<<<512, 256, 0, stream>>>(sqo, w_out, b_out, out);
}

// Round 7
// 1045.474 us; speedup vs baseline: 2.2861x; 1.0146x over previous
//
#include <hip/hip_runtime.h>
#include <hip/hip_bf16.h>

#define NB   16      // batch
#define FDIM 2048    // lstm hidden
#define GDIM 8192    // 4*FDIM gates
#define WSEQ 32      // seq len
#define CDIM 256
#define CBD  64
#define HGT  32

#define PSTR 18        // part[] stride (2-way bank aliasing = free)
#define BARSTRIDE 288  // u32 per stage: 8 group lines + 1 root line, 128B apart
#define AGENTSC __HIP_MEMORY_SCOPE_AGENT

typedef float f32x4 __attribute__((ext_vector_type(4)));
typedef long  l64x2 __attribute__((ext_vector_type(2)));
typedef unsigned char u8;

__device__ __forceinline__ float sigf(float x) { return 1.f / (1.f + __expf(-x)); }

__device__ __forceinline__ u8 f32_to_fp8(float f) {
    int w = __builtin_amdgcn_cvt_pk_fp8_f32(f, f, 0, 0);
    return (u8)(w & 0xff);
}

// ---------------------------------------------------------------------------
// Coalesced weight pack -> fp8 e4m3 (layout as R5/R6).
// W[tile][kc2][lane][16B]; bytes0-7 = frag kc=2kc2, 8-15 = kc=2kc2+1;
// frag byte i of (kc,lane): k = kc*32+(lane>>4)*8+i, col = lane&15.
// ---------------------------------------------------------------------------
__global__ __launch_bounds__(256) void pack_w(
        const float* __restrict__ wih0, const float* __restrict__ whh0,
        const float* __restrict__ wih1, const float* __restrict__ whh1,
        u8* __restrict__ W0, u8* __restrict__ W1) {
    __shared__ u8 FW[16][4112];   // [c][k], +16 pad
    int b = blockIdx.x;           // 0..1023
    int mat = b >> 9, tile = b & 511;
    const float* wih = mat ? wih1 : wih0;
    const float* whh = mat ? whh1 : whh0;
    int p = tile & 1, jt = tile >> 1;
    int tid = threadIdx.x;
    for (int it = 0; it < 32; ++it) {     // 2 src halves x 16 rows
        int c = it & 15, srcsel = it >> 4;
        int gate = p * 2 + (c >> 3);
        int r = gate * FDIM + jt * 8 + (c & 7);
        const float* s = (srcsel ? whh : wih) + (size_t)r * FDIM + tid * 8;
        float4 f0 = *(const float4*)(s);
        float4 f1 = *(const float4*)(s + 4);
        int w0 = __builtin_amdgcn_cvt_pk_fp8_f32(f0.x, f0.y, 0, 0);
        w0     = __builtin_amdgcn_cvt_pk_fp8_f32(f0.z, f0.w, w0, 1);
        int w1 = __builtin_amdgcn_cvt_pk_fp8_f32(f1.x, f1.y, 0, 0);
        w1     = __builtin_amdgcn_cvt_pk_fp8_f32(f1.z, f1.w, w1, 1);
        *(int2*)&FW[c][srcsel * 2048 + tid * 8] = make_int2(w0, w1);
    }
    __syncthreads();
    u8* base = (mat ? W1 : W0) + (size_t)tile * 65536;
#pragma unroll
    for (int w = 0; w < 16; ++w) {
        int q = w * 256 + tid;            // kc2*64 + lane
        int kc2 = q >> 6, lane = q & 63;
        int c = lane & 15, kg = lane >> 4;
        l64x2 v;
        v.x = *(const long*)&FW[c][kc2 * 64 + kg * 8];
        v.y = *(const long*)&FW[c][kc2 * 64 + 32 + kg * 8];
        *(l64x2*)(base + (size_t)q * 16) = v;
    }
}

__global__ void bias_k(const float* __restrict__ bih0, const float* __restrict__ bhh0,
                       const float* __restrict__ bih1, const float* __restrict__ bhh1,
                       float* __restrict__ b0, float* __restrict__ b1) {
    int i = blockIdx.x * blockDim.x + threadIdx.x;
    if (i < GDIM)            b0[i] = bih0[i] + bhh0[i];
    else if (i < 2 * GDIM) { int j = i - GDIM; b1[j] = bih1[j] + bhh1[j]; }
}

// ---------------------------------------------------------------------------
// 1x1 conv-in; emit seq in PACKED A-fragment layout:
//   seqbP[t] : [64 kc][64 lane][8B], byte i of (kc,lane): k = kc*32+(lane>>4)*8+i,
//   row = lane&15 (n). Matches recurrence's x-chunk addressing directly.
// ---------------------------------------------------------------------------
__global__ __launch_bounds__(256) void conv_in(const float* __restrict__ latent,
                        const float* __restrict__ w_in, const float* __restrict__ b_in,
                        u8* __restrict__ seqbP) {
    __shared__ float lat[CDIM * HGT]; // [c][h] 32 KiB
    __shared__ float hv[FDIM];        // 8 KiB
    int b = blockIdx.x; int n = b >> 5; int t = b & 31;
    int tid = threadIdx.x;
    for (int i = 0; i < 32; ++i) {
        int flat = i * 256 + tid;         // c*32+h
        int c = flat >> 5, h = flat & 31;
        lat[flat] = latent[(((size_t)n * CDIM + c) * WSEQ + t) * HGT + h];
    }
    __syncthreads();
    int cb = tid & 63;
    int hb = tid >> 6;
    float acc[8];
#pragma unroll
    for (int k = 0; k < 8; ++k) acc[k] = b_in[cb];
    for (int c = 0; c < CDIM; ++c) {
        float wv = w_in[cb * CDIM + c];
#pragma unroll
        for (int k = 0; k < 8; ++k) acc[k] += lat[c * HGT + (hb + k * 4)] * wv;
    }
#pragma unroll
    for (int k = 0; k < 8; ++k) hv[k * 256 + tid] = acc[k];   // hv[f], f = h*64+cb
    __syncthreads();
    union { u8 by[8]; long l; } pk;
#pragma unroll
    for (int i = 0; i < 8; ++i) pk.by[i] = f32_to_fp8(hv[tid * 8 + i]);
    *(long*)(seqbP + (size_t)t * 32768 + (tid >> 2) * 512 + (tid & 3) * 128 + n * 8) = pk.l;
}

// ---------------------------------------------------------------------------
// Recurrence helpers
// ---------------------------------------------------------------------------
template<bool SC1>
__device__ __forceinline__ void loadA8(const u8* base, long* f) {
#pragma unroll
    for (int i = 0; i < 8; ++i) {
        const long* p = (const long*)(base + (size_t)i * 512);
        f[i] = SC1 ? __hip_atomic_load(p, __ATOMIC_RELAXED, AGENTSC) : *p;
    }
}

__device__ __forceinline__ f32x4 mfma8(long a, long b, f32x4 acc) {
    return __builtin_amdgcn_mfma_f32_16x16x32_fp8_fp8(a, b, acc, 0, 0, 0);
}

__device__ __forceinline__ void mma8r(const long* f, const l64x2* b, f32x4& a0, f32x4& a1) {
#pragma unroll
    for (int i = 0; i < 4; ++i) {
        a0 = mfma8(f[2 * i],     b[i].x, a0);
        a1 = mfma8(f[2 * i + 1], b[i].y, a1);
    }
}

__device__ __forceinline__ void mma8l(const long* f, const l64x2* bb, f32x4& a0, f32x4& a1) {
#pragma unroll
    for (int i = 0; i < 4; ++i) {
        l64x2 bl = bb[(size_t)i * 64];
        a0 = mfma8(f[2 * i],     bl.x, a0);
        a1 = mfma8(f[2 * i + 1], bl.y, a1);
    }
}

__device__ __forceinline__ void store_part(float* part, int wave, int kg, int la, f32x4 acc) {
#pragma unroll
    for (int q = 0; q < 4; ++q) part[(wave * 16 + kg * 4 + q) * PSTR + la] = acc[q];
}

__device__ __forceinline__ void cell_tail(int jt, int tid, const float* part,
        const float* bias, float* cbuf, u8* hA, u8* hB, float* seqSlot) {
    if (tid < 128) {
        int m = tid >> 3, jj = tid & 7;
        float gi = 0.f, gf = 0.f, gg = 0.f, go = 0.f;
#pragma unroll
        for (int e = 0; e < 8; ++e) {
            gi += part[(e * 16 + m) * PSTR + jj];
            gf += part[(e * 16 + m) * PSTR + 8 + jj];
            gg += part[((8 + e) * 16 + m) * PSTR + jj];
            go += part[((8 + e) * 16 + m) * PSTR + 8 + jj];
        }
        int j = jt * 8 + jj;
        gi += bias[j];
        gf += bias[FDIM + j];
        gg += bias[2 * FDIM + j];
        go += bias[3 * FDIM + j];
        float c  = cbuf[m * FDIM + j];
        float cn = sigf(gf) * c + sigf(gi) * tanhf(gg);
        float h  = sigf(go) * tanhf(cn);
        cbuf[m * FDIM + j] = cn;
        u8 hb = f32_to_fp8(h);
        int pos = (jt >> 2) * 512 + (jt & 3) * 128 + tid;
        __hip_atomic_store(hA + 32768 + pos, hb, __ATOMIC_RELAXED, AGENTSC);
        __hip_atomic_store(hB + pos,         hb, __ATOMIC_RELAXED, AGENTSC);
        if (seqSlot) seqSlot[m * FDIM + j] = h;
    }
}

// Hierarchical grid barrier (R6 protocol: RELEASE arrivals, RELAXED polls;
// data coherence carried by the sc1 h-stores / A-loads, so no acquire).
__device__ __forceinline__ void grid_bar(unsigned* base) {
    __syncthreads();
    if (threadIdx.x == 0) {
        unsigned* loc  = base + (blockIdx.x & 7) * 32;
        unsigned* root = base + 256;
        unsigned prev = __hip_atomic_fetch_add(loc, 1u, __ATOMIC_RELEASE, AGENTSC);
        if (prev == 31u)
            __hip_atomic_fetch_add(root, 1u, __ATOMIC_RELEASE, AGENTSC);
        int guard = 0;
        while (__hip_atomic_load(root, __ATOMIC_RELAXED, AGENTSC) < 8u
               && ++guard < (1 << 24))
            __builtin_amdgcn_s_sleep(1);
    }
    __syncthreads();
}

// ---------------------------------------------------------------------------
// Persistent recurrence. 256 blocks x 1024 thr (1 block/CU). Block jt owns
// features jt*8..jt*8+7 for all 4 gates. W1 slice (128 KiB) in LDS; W0 slice
// (128 KiB) PINNED IN REGISTERS (8 x l64x2 per lane x 16 waves) -> zero
// weight memory traffic in steady state. Fwd L0 runs full-K, x-chunks read
// from seqbP (plain cached), h-chunks sc1; no X0 precompute needed.
// ---------------------------------------------------------------------------
__global__ __launch_bounds__(1024, 4) void recurrence(
        const u8* __restrict__ W0, const u8* __restrict__ W1,
        const u8* __restrict__ seqbP,
        const float* __restrict__ b0, const float* __restrict__ b1,
        float* __restrict__ c0, float* __restrict__ c1,
        u8* __restrict__ a00, u8* __restrict__ a01,
        u8* __restrict__ a10, u8* __restrict__ a11,
        float* __restrict__ sqo, unsigned* __restrict__ bar) {
    __shared__ uint4 w1lds[8192];          // 128 KiB W1 slice
    __shared__ float part[16 * 16 * PSTR]; // 18.4 KiB
    const int jt = blockIdx.x, tid = threadIdx.x;
    const int wave = tid >> 6, l = tid & 63;
    const int gp = wave >> 3, ke = wave & 7;   // gate-pair, k-eighth
    const int la = l & 15, kg = l >> 4;
    const int tIdx = jt * 2 + gp;
    {
        const uint4* src = (const uint4*)(W1 + (size_t)jt * 131072);
        for (int i = tid; i < 8192; i += 1024) w1lds[i] = src[i];
    }
    // pin this wave's W0 fragments: kc2 = ke*8 .. ke*8+7
    l64x2 b0pin[8];
    {
        const u8* Bb = W0 + ((size_t)(tIdx * 64 + ke * 8) * 64 + l) * 16;
#pragma unroll
        for (int i = 0; i < 8; ++i) b0pin[i] = *(const l64x2*)(Bb + (size_t)i * 1024);
    }
    __syncthreads();

    u8* a0arr[2] = {a00, a01};
    u8* a1arr[2] = {a10, a11};
    unsigned* bs = bar;
    const l64x2* bb1 = (const l64x2*)w1lds + ((size_t)(gp * 64 + ke * 8) * 64 + l);

    auto l0_phase = [&](const u8* xsrc, const u8* A0, bool xplain, u8* hA, u8* hB) {
        long fa[8], fb[8];
        const u8* base = ((ke < 4) ? xsrc : A0) + (size_t)(ke * 16) * 512 + (size_t)l * 8;
        if (ke < 4 && xplain) { loadA8<false>(base, fa); loadA8<false>(base + 4096, fb); }
        else                  { loadA8<true>(base, fa);  loadA8<true>(base + 4096, fb); }
        f32x4 z = {0.f, 0.f, 0.f, 0.f};
        f32x4 qa = z, qb = z;
        mma8r(fa, b0pin, qa, qb);
        mma8r(fb, b0pin + 4, qa, qb);
        store_part(part, wave, kg, la, qa + qb);
        __syncthreads();
        cell_tail(jt, tid, part, b0, c0, hA, hB, nullptr);
    };
    auto l1_phase = [&](const u8* A1, u8* hA, u8* hB, float* slot) {
        long fa[8], fb[8];
        const u8* base = A1 + (size_t)(ke * 16) * 512 + (size_t)l * 8;
        loadA8<true>(base, fa); loadA8<true>(base + 4096, fb);
        f32x4 z = {0.f, 0.f, 0.f, 0.f};
        f32x4 qa = z, qb = z;
        mma8l(fa, bb1, qa, qb);
        mma8l(fb, bb1 + 4 * 64, qa, qb);
        store_part(part, wave, kg, la, qa + qb);
        __syncthreads();
        cell_tail(jt, tid, part, b1, c1, hA, hB, slot);
    };

    // stage 0: L0[0] (h-half zeros)
    l0_phase(seqbP, a00, true, a01, a10);
    grid_bar(bs); bs += BARSTRIDE;

    // fwd stages s=0..30: L0[s+1] + L1[s], loads co-issued
    for (int s = 0; s <= 30; ++s) {
        int bp = s & 1;
        const u8* A0 = a0arr[1 - bp];
        const u8* xs = seqbP + (size_t)(s + 1) * 32768;
        const u8* A1 = a1arr[bp];
        long f0a[8], f0b[8], f1a[8], f1b[8];
        const u8* base0 = ((ke < 4) ? xs : A0) + (size_t)(ke * 16) * 512 + (size_t)l * 8;
        const u8* base1 = A1 + (size_t)(ke * 16) * 512 + (size_t)l * 8;
        if (ke < 4) { loadA8<false>(base0, f0a); loadA8<false>(base0 + 4096, f0b); }
        else        { loadA8<true>(base0, f0a);  loadA8<true>(base0 + 4096, f0b); }
        loadA8<true>(base1, f1a);
        f32x4 z = {0.f, 0.f, 0.f, 0.f};
        f32x4 q0a = z, q0b = z, q1a = z, q1b = z;
        mma8r(f0a, b0pin, q0a, q0b);
        loadA8<true>(base1 + 4096, f1b);
        mma8r(f0b, b0pin + 4, q0a, q0b);
        mma8l(f1a, bb1, q1a, q1b);
        mma8l(f1b, bb1 + 4 * 64, q1a, q1b);
        store_part(part, wave, kg, la, q0a + q0b);
        __syncthreads();
        cell_tail(jt, tid, part, b0, c0, a0arr[bp], a1arr[1 - bp], nullptr);
        __syncthreads();
        store_part(part, wave, kg, la, q1a + q1b);
        __syncthreads();
        cell_tail(jt, tid, part, b1, c1, a1arr[1 - bp], a0arr[1 - bp], nullptr);
        grid_bar(bs); bs += BARSTRIDE;
    }
    // stage: L1[31] -> first recorded output
    l1_phase(a1arr[1], a1arr[0], a0arr[0], sqo);
    grid_bar(bs); bs += BARSTRIDE;
    // AR region s=32..62
    for (int s = 32; s < 63; ++s) {
        int bp = s & 1;
        l0_phase(a0arr[bp], a0arr[bp], false, a0arr[1 - bp], a1arr[bp]);
        grid_bar(bs); bs += BARSTRIDE;
        l1_phase(a1arr[bp], a1arr[1 - bp], a0arr[1 - bp],
                 sqo + (size_t)(s - 31) * NB * FDIM);
        if (s != 62) { grid_bar(bs); bs += BARSTRIDE; }
    }
}

// copy latent -> out[:, :, 0:32, :]
__global__ void copy_lat(const float* __restrict__ latent, float* __restrict__ out) {
    size_t i = (size_t)blockIdx.x * blockDim.x + threadIdx.x;
    if (i >= (size_t)1048576) return;
    size_t blk = i >> 8;
    size_t within = i & 255;
    float4 v = ((const float4*)latent)[i];
    ((float4*)out)[blk * 512 + within] = v;
}

// gen half: out[n][c][32+t][h] = sum_cb seq_out[t][n][h*64+cb]*w_out[c][cb] + b_out[c]
__global__ __launch_bounds__(256) void gen_out(const float* __restrict__ seq_out,
                        const float* __restrict__ w_out, const float* __restrict__ b_out,
                        float* __restrict__ out) {
    __shared__ float row[32 * 65];
    int b = blockIdx.x; int n = b >> 5, t = b & 31;
    const float* src = seq_out + ((size_t)t * NB + n) * FDIM;
    for (int i = threadIdx.x; i < FDIM; i += 256)
        row[(i >> 6) * 65 + (i & 63)] = src[i];
    __syncthreads();
    for (int it = 0; it < 32; ++it) {
        int o = it * 256 + threadIdx.x;
        int c = o >> 5, h = o & 31;
        float acc = b_out[c];
#pragma unroll
        for (int cb = 0; cb < CBD; ++cb) acc += row[h * 65 + cb] * w_out[c * CBD + cb];
        out[(((size_t)n * CDIM + c) * 64 + 32 + t) * HGT + h] = acc;
    }
}

extern "C" void kernel_launch(void* const* d_in, const int* in_sizes, int n_in,
                              void* d_out, int out_size, void* d_ws, size_t ws_size,
                              hipStream_t stream) {
    const float* latent = (const float*)d_in[0];
    const float* w_in   = (const float*)d_in[1];
    const float* b_in   = (const float*)d_in[2];
    const float* w_ih0  = (const float*)d_in[3];
    const float* w_hh0  = (const float*)d_in[4];
    const float* b_ih0  = (const float*)d_in[5];
    const float* b_hh0  = (const float*)d_in[6];
    const float* w_ih1  = (const float*)d_in[7];
    const float* w_hh1  = (const float*)d_in[8];
    const float* b_ih1  = (const float*)d_in[9];
    const float* b_hh1  = (const float*)d_in[10];
    const float* w_out  = (const float*)d_in[11];
    const float* b_out  = (const float*)d_in[12];
    float* out = (float*)d_out;
    char* ws = (char*)d_ws;

    size_t off = 0;
    u8*    W0   = (u8*)(ws + off); off += (size_t)512 * 65536;             // 32 MiB
    u8*    W1   = (u8*)(ws + off); off += (size_t)512 * 65536;             // 32 MiB
    u8*    seqbP= (u8*)(ws + off); off += (size_t)WSEQ * 32768;            // 1 MiB
    float* sqo  = (float*)(ws + off); off += (size_t)WSEQ * NB * FDIM * 4; // 4 MiB
    char*  zbase = ws + off;
    u8* a00 = (u8*)(ws + off); off += 65536;
    u8* a01 = (u8*)(ws + off); off += 65536;
    u8* a10 = (u8*)(ws + off); off += 65536;
    u8* a11 = (u8*)(ws + off); off += 65536;
    float* c0 = (float*)(ws + off); off += (size_t)NB * FDIM * 4;
    float* c1 = (float*)(ws + off); off += (size_t)NB * FDIM * 4;
    unsigned* bar = (unsigned*)(ws + off); off += (size_t)96 * BARSTRIDE * 4; // 110 KiB
    size_t zbytes = (size_t)(ws + off - zbase);
    float* b0 = (float*)(ws + off); off += (size_t)GDIM * 4;
    float* b1 = (float*)(ws + off); off += (size_t)GDIM * 4;

    if (ws_size < off) {
        hipMemsetAsync(d_out, 0, (size_t)out_size * 4, stream);
        return;
    }

    hipMemsetAsync(zbase, 0, zbytes, stream);
    pack_w<<<1024, 256, 0, stream>>>(w_ih0, w_hh0, w_ih1, w_hh1, W0, W1);
    bias_k<<<64, 256, 0, stream>>>(b_ih0, b_hh0, b_ih1, b_hh1, b0, b1);
    conv_in<<<512, 256, 0, stream>>>(latent, w_in, b_in, seqbP);
    recurrence<<<256, 1024, 0, stream>>>(W0, W1, seqbP, b0, b1, c0, c1,
                                         a00, a01, a10, a11, sqo, bar);
    copy_lat<<<4096, 256, 0, stream>>>(latent, out);
    gen_out<<<512, 256, 0, stream>>>(sqo, w_out, b_out, out);
}

// Round 8
// 884.550 us; speedup vs baseline: 2.7020x; 1.1819x over previous
//
#include <hip/hip_runtime.h>
#include <hip/hip_bf16.h>

#define NB   16      // batch
#define FDIM 2048    // lstm hidden
#define GDIM 8192    // 4*FDIM gates
#define WSEQ 32      // seq len
#define CDIM 256
#define CBD  64
#define HGT  32

#define PSTR 18        // part[] stride (2-way bank aliasing = free)
#define BARSTRIDE 288  // u32 per stage: 8 group lines + 1 root line, 128B apart
#define AGENTSC __HIP_MEMORY_SCOPE_AGENT

typedef float f32x4 __attribute__((ext_vector_type(4)));
typedef long  l64x2 __attribute__((ext_vector_type(2)));
typedef unsigned char u8;

__device__ __forceinline__ float sigf(float x) { return 1.f / (1.f + __expf(-x)); }

__device__ __forceinline__ u8 f32_to_fp8(float f) {
    int w = __builtin_amdgcn_cvt_pk_fp8_f32(f, f, 0, 0);
    return (u8)(w & 0xff);
}

// ---------------------------------------------------------------------------
// Coalesced weight pack -> fp8 e4m3 (layout as R5-R7), 4 rows in flight.
// W[tile][kc2][lane][16B]; bytes0-7 = frag kc=2kc2, 8-15 = kc=2kc2+1;
// frag byte i of (kc,lane): k = kc*32+(lane>>4)*8+i, col = lane&15.
// ---------------------------------------------------------------------------
__global__ __launch_bounds__(256) void pack_w(
        const float* __restrict__ wih0, const float* __restrict__ whh0,
        const float* __restrict__ wih1, const float* __restrict__ whh1,
        u8* __restrict__ W0, u8* __restrict__ W1) {
    __shared__ u8 FW[16][4112];   // [c][k], +16 pad
    int b = blockIdx.x;           // 0..1023
    int mat = b >> 9, tile = b & 511;
    const float* wih = mat ? wih1 : wih0;
    const float* whh = mat ? whh1 : whh0;
    int p = tile & 1, jt = tile >> 1;
    int tid = threadIdx.x;
    for (int it = 0; it < 32; it += 4) {   // 2 src halves x 16 rows, 4-deep ILP
        float4 f[4][2];
#pragma unroll
        for (int r = 0; r < 4; ++r) {
            int c = (it + r) & 15, srcsel = (it + r) >> 4;
            int gate = p * 2 + (c >> 3);
            int rr = gate * FDIM + jt * 8 + (c & 7);
            const float* s = (srcsel ? whh : wih) + (size_t)rr * FDIM + tid * 8;
            f[r][0] = *(const float4*)(s);
            f[r][1] = *(const float4*)(s + 4);
        }
#pragma unroll
        for (int r = 0; r < 4; ++r) {
            int c = (it + r) & 15, srcsel = (it + r) >> 4;
            int w0 = __builtin_amdgcn_cvt_pk_fp8_f32(f[r][0].x, f[r][0].y, 0, 0);
            w0     = __builtin_amdgcn_cvt_pk_fp8_f32(f[r][0].z, f[r][0].w, w0, 1);
            int w1 = __builtin_amdgcn_cvt_pk_fp8_f32(f[r][1].x, f[r][1].y, 0, 0);
            w1     = __builtin_amdgcn_cvt_pk_fp8_f32(f[r][1].z, f[r][1].w, w1, 1);
            *(int2*)&FW[c][srcsel * 2048 + tid * 8] = make_int2(w0, w1);
        }
    }
    __syncthreads();
    u8* base = (mat ? W1 : W0) + (size_t)tile * 65536;
#pragma unroll
    for (int w = 0; w < 16; ++w) {
        int q = w * 256 + tid;            // kc2*64 + lane
        int kc2 = q >> 6, lane = q & 63;
        int c = lane & 15, kg = lane >> 4;
        l64x2 v;
        v.x = *(const long*)&FW[c][kc2 * 64 + kg * 8];
        v.y = *(const long*)&FW[c][kc2 * 64 + 32 + kg * 8];
        *(l64x2*)(base + (size_t)q * 16) = v;
    }
}

__global__ void bias_k(const float* __restrict__ bih0, const float* __restrict__ bhh0,
                       const float* __restrict__ bih1, const float* __restrict__ bhh1,
                       float* __restrict__ b0, float* __restrict__ b1) {
    int i = blockIdx.x * blockDim.x + threadIdx.x;
    if (i < GDIM)            b0[i] = bih0[i] + bhh0[i];
    else if (i < 2 * GDIM) { int j = i - GDIM; b1[j] = bih1[j] + bhh1[j]; }
}

// ---------------------------------------------------------------------------
// 1x1 conv-in; emit seq in PACKED A-fragment layout:
//   seqbP[t] : [64 kc][64 lane][8B], byte i of (kc,lane): k = kc*32+(lane>>4)*8+i
// ---------------------------------------------------------------------------
__global__ __launch_bounds__(256) void conv_in(const float* __restrict__ latent,
                        const float* __restrict__ w_in, const float* __restrict__ b_in,
                        u8* __restrict__ seqbP) {
    __shared__ float lat[CDIM * HGT]; // [c][h] 32 KiB
    __shared__ float hv[FDIM];        // 8 KiB
    int b = blockIdx.x; int n = b >> 5; int t = b & 31;
    int tid = threadIdx.x;
    for (int i = 0; i < 32; ++i) {
        int flat = i * 256 + tid;         // c*32+h
        int c = flat >> 5, h = flat & 31;
        lat[flat] = latent[(((size_t)n * CDIM + c) * WSEQ + t) * HGT + h];
    }
    __syncthreads();
    int cb = tid & 63;
    int hb = tid >> 6;
    float acc[8];
#pragma unroll
    for (int k = 0; k < 8; ++k) acc[k] = b_in[cb];
    for (int c = 0; c < CDIM; ++c) {
        float wv = w_in[cb * CDIM + c];
#pragma unroll
        for (int k = 0; k < 8; ++k) acc[k] += lat[c * HGT + (hb + k * 4)] * wv;
    }
#pragma unroll
    for (int k = 0; k < 8; ++k) hv[k * 256 + tid] = acc[k];   // hv[f], f = h*64+cb
    __syncthreads();
    union { u8 by[8]; long l; } pk;
#pragma unroll
    for (int i = 0; i < 8; ++i) pk.by[i] = f32_to_fp8(hv[tid * 8 + i]);
    *(long*)(seqbP + (size_t)t * 32768 + (tid >> 2) * 512 + (tid & 3) * 128 + n * 8) = pk.l;
}

// ---------------------------------------------------------------------------
// Async load cluster: issue 8 independent 8B loads with NO intervening waits.
// SC=true -> `sc1` (agent-coherent, L2-bypass, reads L3) -- same semantics as
// __hip_atomic_load(RELAXED, AGENT) but the compiler can't serialize them.
// Caller MUST call vm_wait0() before consuming f[].
// ---------------------------------------------------------------------------
template<bool SC>
__device__ __forceinline__ void loadA8_async(const u8* base, long* f) {
#pragma unroll
    for (int i = 0; i < 8; ++i) {
        const u8* p = base + (size_t)i * 512;
        if (SC)
            asm volatile("global_load_dwordx2 %0, %1, off sc1" : "=v"(f[i]) : "v"(p));
        else
            asm volatile("global_load_dwordx2 %0, %1, off" : "=v"(f[i]) : "v"(p));
    }
}

__device__ __forceinline__ void vm_wait0() {
    asm volatile("s_waitcnt vmcnt(0)" ::: "memory");
    __builtin_amdgcn_sched_barrier(0);   // keep MFMAs from hoisting above the wait
}

__device__ __forceinline__ f32x4 mfma8(long a, long b, f32x4 acc) {
    return __builtin_amdgcn_mfma_f32_16x16x32_fp8_fp8(a, b, acc, 0, 0, 0);
}

__device__ __forceinline__ void mma8r(const long* f, const l64x2* b, f32x4& a0, f32x4& a1) {
#pragma unroll
    for (int i = 0; i < 4; ++i) {
        a0 = mfma8(f[2 * i],     b[i].x, a0);
        a1 = mfma8(f[2 * i + 1], b[i].y, a1);
    }
}

__device__ __forceinline__ void mma8l(const long* f, const l64x2* bb, f32x4& a0, f32x4& a1) {
#pragma unroll
    for (int i = 0; i < 4; ++i) {
        l64x2 bl = bb[(size_t)i * 64];
        a0 = mfma8(f[2 * i],     bl.x, a0);
        a1 = mfma8(f[2 * i + 1], bl.y, a1);
    }
}

__device__ __forceinline__ void store_part(float* part, int wave, int kg, int la, f32x4 acc) {
#pragma unroll
    for (int q = 0; q < 4; ++q) part[(wave * 16 + kg * 4 + q) * PSTR + la] = acc[q];
}

// LSTM cell tail: c-state and biases live in REGISTERS (persistent kernel).
__device__ __forceinline__ void cell_tail(int jt, int tid, const float* part,
        float bi, float bf, float bg, float bo, float& cr,
        u8* hA, u8* hB, float* seqSlot) {
    if (tid < 128) {
        int m = tid >> 3, jj = tid & 7;
        float gi = 0.f, gf = 0.f, gg = 0.f, go = 0.f;
#pragma unroll
        for (int e = 0; e < 8; ++e) {
            gi += part[(e * 16 + m) * PSTR + jj];
            gf += part[(e * 16 + m) * PSTR + 8 + jj];
            gg += part[((8 + e) * 16 + m) * PSTR + jj];
            go += part[((8 + e) * 16 + m) * PSTR + 8 + jj];
        }
        float cn = sigf(gf + bf) * cr + sigf(gi + bi) * tanhf(gg + bg);
        float h  = sigf(go + bo) * tanhf(cn);
        cr = cn;
        u8 hb = f32_to_fp8(h);
        int pos = (jt >> 2) * 512 + (jt & 3) * 128 + tid;
        __hip_atomic_store(hA + 32768 + pos, hb, __ATOMIC_RELAXED, AGENTSC);
        __hip_atomic_store(hB + pos,         hb, __ATOMIC_RELAXED, AGENTSC);
        if (seqSlot) {
            int j = jt * 8 + jj;
            seqSlot[m * FDIM + j] = h;
        }
    }
}

// Hierarchical grid barrier (R6 protocol: RELEASE arrivals, RELAXED polls;
// data coherence carried by the sc1 h-stores / sc1 A-loads, so no acquire).
__device__ __forceinline__ void grid_bar(unsigned* base) {
    __syncthreads();
    if (threadIdx.x == 0) {
        unsigned* loc  = base + (blockIdx.x & 7) * 32;
        unsigned* root = base + 256;
        unsigned prev = __hip_atomic_fetch_add(loc, 1u, __ATOMIC_RELEASE, AGENTSC);
        if (prev == 31u)
            __hip_atomic_fetch_add(root, 1u, __ATOMIC_RELEASE, AGENTSC);
        int guard = 0;
        while (__hip_atomic_load(root, __ATOMIC_RELAXED, AGENTSC) < 8u
               && ++guard < (1 << 24))
            __builtin_amdgcn_s_sleep(1);
    }
    __syncthreads();
}

// ---------------------------------------------------------------------------
// Persistent recurrence. 256 blocks x 1024 thr (1 block/CU). Block jt owns
// features jt*8..jt*8+7 for all 4 gates. W1 slice (128 KiB) in LDS; W0 slice
// (128 KiB) pinned in registers; c-state + biases in registers. All
// cross-block A loads are ASYNC-batched sc1 (1 L3 round trip per phase).
// ---------------------------------------------------------------------------
__global__ __launch_bounds__(1024, 4) void recurrence(
        const u8* __restrict__ W0, const u8* __restrict__ W1,
        const u8* __restrict__ seqbP,
        const float* __restrict__ b0, const float* __restrict__ b1,
        u8* __restrict__ a00, u8* __restrict__ a01,
        u8* __restrict__ a10, u8* __restrict__ a11,
        float* __restrict__ sqo, unsigned* __restrict__ bar) {
    __shared__ uint4 w1lds[8192];          // 128 KiB W1 slice
    __shared__ float part[16 * 16 * PSTR]; // 18.4 KiB
    const int jt = blockIdx.x, tid = threadIdx.x;
    const int wave = tid >> 6, l = tid & 63;
    const int gp = wave >> 3, ke = wave & 7;   // gate-pair, k-eighth
    const int la = l & 15, kg = l >> 4;
    const int tIdx = jt * 2 + gp;
    (void)la;
    {
        const uint4* src = (const uint4*)(W1 + (size_t)jt * 131072);
        for (int i = tid; i < 8192; i += 1024) w1lds[i] = src[i];
    }
    // pin this wave's W0 fragments: kc2 = ke*8 .. ke*8+7
    l64x2 b0pin[8];
    {
        const u8* Bb = W0 + ((size_t)(tIdx * 64 + ke * 8) * 64 + l) * 16;
#pragma unroll
        for (int i = 0; i < 8; ++i) b0pin[i] = *(const l64x2*)(Bb + (size_t)i * 1024);
    }
    // registers: cell state + biases
    float cr0 = 0.f, cr1 = 0.f;
    float bi0 = 0, bf0 = 0, bg0 = 0, bo0 = 0, bi1 = 0, bf1 = 0, bg1 = 0, bo1 = 0;
    if (tid < 128) {
        int j = jt * 8 + (tid & 7);
        bi0 = b0[j]; bf0 = b0[FDIM + j]; bg0 = b0[2 * FDIM + j]; bo0 = b0[3 * FDIM + j];
        bi1 = b1[j]; bf1 = b1[FDIM + j]; bg1 = b1[2 * FDIM + j]; bo1 = b1[3 * FDIM + j];
    }
    __syncthreads();

    u8* a0arr[2] = {a00, a01};
    u8* a1arr[2] = {a10, a11};
    unsigned* bs = bar;
    const l64x2* bb1 = (const l64x2*)w1lds + ((size_t)(gp * 64 + ke * 8) * 64 + l);
    const f32x4 z = {0.f, 0.f, 0.f, 0.f};

    auto l0_phase = [&](const u8* xsrc, const u8* A0, bool xplain, u8* hA, u8* hB) {
        long fa[8], fb[8];
        const u8* base = ((ke < 4) ? xsrc : A0) + (size_t)(ke * 16) * 512 + (size_t)l * 8;
        if (ke < 4 && xplain) { loadA8_async<false>(base, fa); loadA8_async<false>(base + 4096, fb); }
        else                  { loadA8_async<true>(base, fa);  loadA8_async<true>(base + 4096, fb); }
        vm_wait0();
        f32x4 qa = z, qb = z;
        mma8r(fa, b0pin, qa, qb);
        mma8r(fb, b0pin + 4, qa, qb);
        store_part(part, wave, kg, la, qa + qb);
        __syncthreads();
        cell_tail(jt, tid, part, bi0, bf0, bg0, bo0, cr0, hA, hB, nullptr);
    };
    auto l1_phase = [&](const u8* A1, u8* hA, u8* hB, float* slot) {
        long fa[8], fb[8];
        const u8* base = A1 + (size_t)(ke * 16) * 512 + (size_t)l * 8;
        loadA8_async<true>(base, fa); loadA8_async<true>(base + 4096, fb);
        vm_wait0();
        f32x4 qa = z, qb = z;
        mma8l(fa, bb1, qa, qb);
        mma8l(fb, bb1 + 4 * 64, qa, qb);
        store_part(part, wave, kg, la, qa + qb);
        __syncthreads();
        cell_tail(jt, tid, part, bi1, bf1, bg1, bo1, cr1, hA, hB, slot);
    };

    // stage 0: L0[0] (h-half zeros)
    l0_phase(seqbP, a00, true, a01, a10);
    grid_bar(bs); bs += BARSTRIDE;

    // fwd stages s=0..30: L0[s+1] + L1[s]; all 32 loads issued as ONE cluster
    for (int s = 0; s <= 30; ++s) {
        int bp = s & 1;
        const u8* A0 = a0arr[1 - bp];
        const u8* xs = seqbP + (size_t)(s + 1) * 32768;
        const u8* A1 = a1arr[bp];
        long f0a[8], f0b[8], f1a[8], f1b[8];
        const u8* base0 = ((ke < 4) ? xs : A0) + (size_t)(ke * 16) * 512 + (size_t)l * 8;
        const u8* base1 = A1 + (size_t)(ke * 16) * 512 + (size_t)l * 8;
        if (ke < 4) { loadA8_async<false>(base0, f0a); loadA8_async<false>(base0 + 4096, f0b); }
        else        { loadA8_async<true>(base0, f0a);  loadA8_async<true>(base0 + 4096, f0b); }
        loadA8_async<true>(base1, f1a);
        loadA8_async<true>(base1 + 4096, f1b);
        vm_wait0();
        f32x4 q0a = z, q0b = z, q1a = z, q1b = z;
        mma8r(f0a, b0pin, q0a, q0b);
        mma8r(f0b, b0pin + 4, q0a, q0b);
        mma8l(f1a, bb1, q1a, q1b);
        mma8l(f1b, bb1 + 4 * 64, q1a, q1b);
        store_part(part, wave, kg, la, q0a + q0b);
        __syncthreads();
        cell_tail(jt, tid, part, bi0, bf0, bg0, bo0, cr0, a0arr[bp], a1arr[1 - bp], nullptr);
        __syncthreads();
        store_part(part, wave, kg, la, q1a + q1b);
        __syncthreads();
        cell_tail(jt, tid, part, bi1, bf1, bg1, bo1, cr1, a1arr[1 - bp], a0arr[1 - bp], nullptr);
        grid_bar(bs); bs += BARSTRIDE;
    }
    // stage: L1[31] -> first recorded output
    l1_phase(a1arr[1], a1arr[0], a0arr[0], sqo);
    grid_bar(bs); bs += BARSTRIDE;
    // AR region s=32..62
    for (int s = 32; s < 63; ++s) {
        int bp = s & 1;
        l0_phase(a0arr[bp], a0arr[bp], false, a0arr[1 - bp], a1arr[bp]);
        grid_bar(bs); bs += BARSTRIDE;
        l1_phase(a1arr[bp], a1arr[1 - bp], a0arr[1 - bp],
                 sqo + (size_t)(s - 31) * NB * FDIM);
        if (s != 62) { grid_bar(bs); bs += BARSTRIDE; }
    }
}

// copy latent -> out[:, :, 0:32, :]
__global__ void copy_lat(const float* __restrict__ latent, float* __restrict__ out) {
    size_t i = (size_t)blockIdx.x * blockDim.x + threadIdx.x;
    if (i >= (size_t)1048576) return;
    size_t blk = i >> 8;
    size_t within = i & 255;
    float4 v = ((const float4*)latent)[i];
    ((float4*)out)[blk * 512 + within] = v;
}

// gen half: out[n][c][32+t][h] = sum_cb seq_out[t][n][h*64+cb]*w_out[c][cb] + b_out[c]
__global__ __launch_bounds__(256) void gen_out(const float* __restrict__ seq_out,
                        const float* __restrict__ w_out, const float* __restrict__ b_out,
                        float* __restrict__ out) {
    __shared__ float row[32 * 65];
    int b = blockIdx.x; int n = b >> 5, t = b & 31;
    const float* src = seq_out + ((size_t)t * NB + n) * FDIM;
    for (int i = threadIdx.x; i < FDIM; i += 256)
        row[(i >> 6) * 65 + (i & 63)] = src[i];
    __syncthreads();
    for (int it = 0; it < 32; ++it) {
        int o = it * 256 + threadIdx.x;
        int c = o >> 5, h = o & 31;
        float acc = b_out[c];
#pragma unroll
        for (int cb = 0; cb < CBD; ++cb) acc += row[h * 65 + cb] * w_out[c * CBD + cb];
        out[(((size_t)n * CDIM + c) * 64 + 32 + t) * HGT + h] = acc;
    }
}

extern "C" void kernel_launch(void* const* d_in, const int* in_sizes, int n_in,
                              void* d_out, int out_size, void* d_ws, size_t ws_size,
                              hipStream_t stream) {
    const float* latent = (const float*)d_in[0];
    const float* w_in   = (const float*)d_in[1];
    const float* b_in   = (const float*)d_in[2];
    const float* w_ih0  = (const float*)d_in[3];
    const float* w_hh0  = (const float*)d_in[4];
    const float* b_ih0  = (const float*)d_in[5];
    const float* b_hh0  = (const float*)d_in[6];
    const float* w_ih1  = (const float*)d_in[7];
    const float* w_hh1  = (const float*)d_in[8];
    const float* b_ih1  = (const float*)d_in[9];
    const float* b_hh1  = (const float*)d_in[10];
    const float* w_out  = (const float*)d_in[11];
    const float* b_out  = (const float*)d_in[12];
    float* out = (float*)d_out;
    char* ws = (char*)d_ws;

    size_t off = 0;
    u8*    W0   = (u8*)(ws + off); off += (size_t)512 * 65536;             // 32 MiB
    u8*    W1   = (u8*)(ws + off); off += (size_t)512 * 65536;             // 32 MiB
    u8*    seqbP= (u8*)(ws + off); off += (size_t)WSEQ * 32768;            // 1 MiB
    float* sqo  = (float*)(ws + off); off += (size_t)WSEQ * NB * FDIM * 4; // 4 MiB
    char*  zbase = ws + off;
    u8* a00 = (u8*)(ws + off); off += 65536;
    u8* a01 = (u8*)(ws + off); off += 65536;
    u8* a10 = (u8*)(ws + off); off += 65536;
    u8* a11 = (u8*)(ws + off); off += 65536;
    unsigned* bar = (unsigned*)(ws + off); off += (size_t)96 * BARSTRIDE * 4; // 110 KiB
    size_t zbytes = (size_t)(ws + off - zbase);
    float* b0 = (float*)(ws + off); off += (size_t)GDIM * 4;
    float* b1 = (float*)(ws + off); off += (size_t)GDIM * 4;

    if (ws_size < off) {
        hipMemsetAsync(d_out, 0, (size_t)out_size * 4, stream);
        return;
    }

    hipMemsetAsync(zbase, 0, zbytes, stream);
    pack_w<<<1024, 256, 0, stream>>>(w_ih0, w_hh0, w_ih1, w_hh1, W0, W1);
    bias_k<<<64, 256, 0, stream>>>(b_ih0, b_hh0, b_ih1, b_hh1, b0, b1);
    conv_in<<<512, 256, 0, stream>>>(latent, w_in, b_in, seqbP);
    recurrence<<<256, 1024, 0, stream>>>(W0, W1, seqbP, b0, b1,
                                         a00, a01, a10, a11, sqo, bar);
    copy_lat<<<4096, 256, 0, stream>>>(latent, out);
    gen_out<<<512, 256, 0, stream>>>(sqo, w_out, b_out, out);
}